// Round 9
// baseline (143.688 us; speedup 1.0000x reference)
//
#include <hip/hip_runtime.h>
#include <math.h>

#define HB 256   // hidden
#define UB 128   // attention units
#define BB 16    // batch
#define TD 128   // decoder steps
#define TE 1024  // encoder steps

#define CLAMP_W 7.0f
#define L2E2 2.8853900817779268f        // 2*log2(e)
#define ALPHA 1.52587890625e-05f        // 2^-16 (folded into Ea)
#define NEG2ALPHA (-3.0517578125e-05f)  // -2*ALPHA

// zero-instruction scheduling pins (v8-proven): force load completed here.
#define PINV(x) asm volatile("" : "+v"(x))
#define PINS(x) asm volatile("" : "+s"(x))
#define PINV4(q) do { PINV((q).x); PINV((q).y); PINV((q).z); PINV((q).w); } while (0)
#define PINS4(q) do { PINS((q).x); PINS((q).y); PINS((q).z); PINS((q).w); } while (0)

// staged operand: exp2(2*log2e*clamp(w,+-7) + shift); tanh(a+e)=1-2/(EaEb+1).
// clamp +-7 never triggers on this data; shift=-16 scales Ea so the 4-way
// merged denominator stays bounded. Numerics identical to R4/R6/R8 (passed).
__device__ __forceinline__ float stage_exp(float w, float shift) {
    float t = fminf(fmaxf(w, -CLAMP_W), CLAMP_W);
    return exp2f(fmaf(t, L2E2, shift));
}

// ---------------- projections (dec + enc, one grid) ----------------
// Thread = u column (0..127): W loads perfectly coalesced (128x4B per h-row).
// Rows are block-uniform: X reads are uniform-address (scalar/L1-broadcast
// path, each 64B line reused by 4 consecutive h-iters -> L1-hot). No LDS,
// no gathers. 32 rows/block, 128-thr blocks, 576 blocks = 1152 waves.
#define RPB 32
#define DEC_BLOCKS (BB * TD / RPB)   // 64
#define ENC_BLOCKS (BB * TE / RPB)   // 512

__global__ __launch_bounds__(128) void proj_v9(
    const float* __restrict__ dec, const float* __restrict__ enc,
    const float* __restrict__ W1, const float* __restrict__ b1,
    const float* __restrict__ W2, const float* __restrict__ b2,
    float* __restrict__ Ea, float* __restrict__ Eb) {
    const int blk = blockIdx.x;
    const bool is_dec = blk < DEC_BLOCKS;
    const int rel = is_dec ? blk : blk - DEC_BLOCKS;
    const float* __restrict__ X    = is_dec ? dec : enc;
    const float* __restrict__ W    = is_dec ? W1 : W2;
    const float* __restrict__ bias = is_dec ? b1 : b2;

    const int u = threadIdx.x;                 // u column
    const long row0 = (long)rel * RPB;
    const float* __restrict__ xb = X + row0 * HB;   // block-uniform base
    const float* __restrict__ wp = W + u;           // per-lane, coalesced

    float acc[RPB];
    #pragma unroll
    for (int r = 0; r < RPB; ++r) acc[r] = 0.f;

    float wC[4], wN[4];
    #pragma unroll
    for (int k = 0; k < 4; ++k) wC[k] = wp[k * UB];

    for (int h = 0; h < HB; h += 4) {
        const int hn = (h + 4 < HB) ? h + 4 : 0;   // wrap: harmless reload
        #pragma unroll
        for (int k = 0; k < 4; ++k) wN[k] = wp[(hn + k) * UB];
        #pragma unroll
        for (int r = 0; r < RPB; ++r) {
            float4 x4 = *reinterpret_cast<const float4*>(xb + r * HB + h);  // uniform
            acc[r] = fmaf(x4.w, wC[3], fmaf(x4.z, wC[2],
                     fmaf(x4.y, wC[1], fmaf(x4.x, wC[0], acc[r]))));
        }
        PINV(wN[0]); PINV(wN[1]); PINV(wN[2]); PINV(wN[3]);
        #pragma unroll
        for (int k = 0; k < 4; ++k) wC[k] = wN[k];
    }

    const float bv = bias[u];
    const float sh = is_dec ? -16.f : 0.f;
    // output layout [b][u4][pos][4]; 4-adjacent threads write 16B groups
    const int POS  = is_dec ? TD : TE;
    const long bq  = row0 / POS;
    const int pos0 = (int)(row0 % POS);
    float* __restrict__ dst = (is_dec ? Ea : Eb)
        + ((bq * 32 + (u >> 2)) * (long)POS) * 4 + (u & 3);
    #pragma unroll
    for (int r = 0; r < RPB; ++r)
        dst[(long)(pos0 + r) * 4] = stage_exp(acc[r] + bv, sh);
}

// ---------------- raw scores (TT=16) ----------------
// Grid 256 = [b16][tgrp8][shalf2]; block 512 thr; s = shalf*512 + tid;
// thread owns 16 t-rows. Per u4-iter: a-tile (16 rows x 4u = 256B contiguous,
// block-uniform -> scalar loads) single-buffered with one-pin drain; e
// (per-lane coalesced dwordx4) + V depth-1 double-buffered (v8 pattern).
// e traffic halves vs TT=8: 64MB total, under the per-CU L2 stream limit.
// Inner math: 4-way exact division merge, 14 VALU + 1 rcp per 4u per row.
__global__ __launch_bounds__(512) void score_v9(
    const float* __restrict__ Ea4,   // [B][32][TD][4], 2^-16-scaled
    const float4* __restrict__ Eb4,  // [B][32][TE]
    const float* __restrict__ V,     // [UB]
    float* __restrict__ outraw) {    // [B, TD, TE] raw scores
    const int tid = threadIdx.x;
    const int i = blockIdx.x;
    const int xcd = i & 7, j = i >> 3;          // XCD-pinned: 2 b per XCD
    const int b     = 2 * xcd + (j >> 4);
    const int tgrp  = (j >> 1) & 7;
    const int shalf = j & 1;
    const int t0 = tgrp * 16;
    const int s  = shalf * 512 + tid;

    const float*  ab = Ea4 + ((long)b * 32 * TD + t0) * 4;   // + u4*TD*4
    const float4* ep = Eb4 + (long)b * 32 * TE + s;          // + u4*TE
    const float alphav = ALPHA;

    float acc[16];
    #pragma unroll
    for (int t = 0; t < 16; ++t) acc[t] = 0.f;

    float4 a[16], vC, vN, eC, eN;
    vC = *reinterpret_cast<const float4*>(V);
    eC = ep[0];

    for (int u4 = 0; u4 < 32; ++u4) {
        const int p = (u4 + 1 < 32) ? u4 + 1 : 0;   // wrap: harmless reload
        // issue next e/V and current a-tile
        eN = ep[(long)p * TE];
        vN = *reinterpret_cast<const float4*>(V + p * 4);
        const float* _a = ab + (long)u4 * (TD * 4);
        #pragma unroll
        for (int t = 0; t < 16; ++t)
            a[t] = *reinterpret_cast<const float4*>(_a + t * 4);  // uniform
        PINS4(a[15]);   // last-issued: waiting on it drains all a-loads
        #pragma unroll
        for (int t = 0; t < 16; ++t) {
            float4 A = a[t];
            float X0 = fmaf(A.x, eC.x, alphav);
            float X1 = fmaf(A.y, eC.y, alphav);
            float X2 = fmaf(A.z, eC.z, alphav);
            float X3 = fmaf(A.w, eC.w, alphav);
            float P01 = X0 * X1, P23 = X2 * X3;
            float N01 = fmaf(vC.x, X1, vC.y * X0);
            float N23 = fmaf(vC.z, X3, vC.w * X2);
            float N   = fmaf(N01, P23, N23 * P01);
            acc[t] = fmaf(N, __builtin_amdgcn_rcpf(P01 * P23), acc[t]);
        }
        PINV4(eN);
        PINS4(vN);
        eC = eN; vC = vN;
    }

    float* orow = outraw + ((long)b * TD + t0) * TE + s;
    #pragma unroll
    for (int t = 0; t < 16; ++t)
        orow[(long)t * TE] = NEG2ALPHA * acc[t];    // coalesced per row
}

// ---------------- in-place row softmax on d_out (R7-proven) ----------------
__global__ __launch_bounds__(1024) void softmax_v9(float* __restrict__ out) {
    const long row = blockIdx.x;             // b*TD + t
    float* p = out + row * TE;
    const int tid = threadIdx.x;
    const int wv = tid >> 6, l = tid & 63;

    float x = p[tid];
    __shared__ float red[16];
    float m = x;
    #pragma unroll
    for (int off = 32; off > 0; off >>= 1) m = fmaxf(m, __shfl_xor(m, off, 64));
    if (l == 0) red[wv] = m;
    __syncthreads();
    #pragma unroll
    for (int k = 0; k < 16; ++k) m = fmaxf(m, red[k]);
    __syncthreads();
    float e = __expf(x - m);
    float si = e;
    #pragma unroll
    for (int off = 32; off > 0; off >>= 1) si += __shfl_xor(si, off, 64);
    if (l == 0) red[wv] = si;
    __syncthreads();
    si = 0.f;
    #pragma unroll
    for (int k = 0; k < 16; ++k) si += red[k];
    p[tid] = e * (1.f / si);
}

extern "C" void kernel_launch(void* const* d_in, const int* in_sizes, int n_in,
                              void* d_out, int out_size, void* d_ws, size_t ws_size,
                              hipStream_t stream) {
    const float* dec = (const float*)d_in[0];
    const float* enc = (const float*)d_in[1];
    const float* W1  = (const float*)d_in[2];
    const float* b1  = (const float*)d_in[3];
    const float* W2  = (const float*)d_in[4];
    const float* b2  = (const float*)d_in[5];
    const float* V   = (const float*)d_in[6];
    // d_in[7] = bv : softmax-invariant, unused
    float* out = (float*)d_out;

    float* Ea = (float*)d_ws;                  // [B][32][TD][4]  1 MB (2^-16-scaled)
    float* Eb = Ea + (long)BB * 32 * TD * 4;   // [B][32][TE][4]  8 MB

    proj_v9<<<DEC_BLOCKS + ENC_BLOCKS, 128, 0, stream>>>(dec, enc, W1, b1, W2, b2, Ea, Eb);
    score_v9<<<256, 512, 0, stream>>>(Ea, (const float4*)Eb, V, out);
    softmax_v9<<<BB * TD, 1024, 0, stream>>>(out);
}

// Round 10
// 90.135 us; speedup vs baseline: 1.5941x; 1.5941x over previous
//
#include <hip/hip_runtime.h>
#include <math.h>

#define HB 256   // hidden
#define UB 128   // attention units
#define BB 16    // batch
#define TD 128   // decoder steps
#define TE 1024  // encoder steps

#define CLAMP_W 7.0f
#define L2E2 2.8853900817779268f        // 2*log2(e)
#define ALPHA 1.52587890625e-05f        // 2^-16 (folded into Ea)
#define NEG2ALPHA (-3.0517578125e-05f)  // -2*ALPHA

// zero-instruction scheduling pins (v8-proven): force load completed here.
#define PINV(x) asm volatile("" : "+v"(x))
#define PINS(x) asm volatile("" : "+s"(x))
#define PINV4(q) do { PINV((q).x); PINV((q).y); PINV((q).z); PINV((q).w); } while (0)
#define PINS4(q) do { PINS((q).x); PINS((q).y); PINS((q).z); PINS((q).w); } while (0)

// staged operand: exp2(2*log2e*clamp(w,+-7) + shift); tanh(a+e)=1-2/(EaEb+1).
// clamp +-7 never triggers on this data; shift=-16 scales Ea so the 4-way
// merged denominator stays bounded. Numerics identical to R4/R6/R8/R9 (passed).
__device__ __forceinline__ float stage_exp(float w, float shift) {
    float t = fminf(fmaxf(w, -CLAMP_W), CLAMP_W);
    return exp2f(fmaf(t, L2E2, shift));
}

// ---------------- projections (dec + enc, one grid) ----------------
// Register-tiled GEMM, 32 rows x 128 u per 256-thr block.
// X tile staged ONCE in padded LDS (stride 260: rows 0..7 of a wave land on
// disjoint bank-quads -> conflict-free b128 broadcast reads). Thread =
// (ut 0..15 -> 8 u, rt 0..15 -> 2 rows). Per 4-h step: 8 coalesced W dwordx4
// (VMEM) + 2 ds_read_b128 (X) -> 64 FMA. LDS pipe ~75% at full VALU; W and X
// both depth-1 software-pipelined with pins. One barrier total.
#define RWS 32
#define DEC_BLOCKS (BB * TD / RWS)   // 64
#define ENC_BLOCKS (BB * TE / RWS)   // 512

__global__ __launch_bounds__(256) void proj_v10(
    const float* __restrict__ dec, const float* __restrict__ enc,
    const float* __restrict__ W1, const float* __restrict__ b1,
    const float* __restrict__ W2, const float* __restrict__ b2,
    float* __restrict__ Ea, float* __restrict__ Eb) {
    const int blk = blockIdx.x;
    const bool is_dec = blk < DEC_BLOCKS;
    const int rel = is_dec ? blk : blk - DEC_BLOCKS;
    const float* __restrict__ X    = is_dec ? dec : enc;
    const float* __restrict__ W    = is_dec ? W1 : W2;
    const float* __restrict__ bias = is_dec ? b1 : b2;

    __shared__ float xs[RWS][HB + 4];        // stride 260: %32 = 4
    const int tid = threadIdx.x;
    const long row0 = (long)rel * RWS;

    {   // stage 32x256 floats; each wave writes full rows -> conflict-free
        const float4* src = reinterpret_cast<const float4*>(X + row0 * HB);
        #pragma unroll
        for (int i = 0; i < 8; ++i) {
            int idx = i * 256 + tid;
            int r = idx >> 6, c = idx & 63;
            *reinterpret_cast<float4*>(&xs[r][c * 4]) = src[idx];
        }
    }
    __syncthreads();

    const int ut = tid & 15, rt = tid >> 4;
    const int u0 = ut * 8;
    const int r0 = rt * 2;
    const float* __restrict__ wp = W + u0;

    float acc[2][8];
    #pragma unroll
    for (int r = 0; r < 2; ++r)
        #pragma unroll
        for (int j = 0; j < 8; ++j) acc[r][j] = 0.f;

    float4 wC[4][2], wN[4][2], xC[2], xN[2];
    #pragma unroll
    for (int k = 0; k < 4; ++k) {
        wC[k][0] = *reinterpret_cast<const float4*>(wp + k * UB);
        wC[k][1] = *reinterpret_cast<const float4*>(wp + k * UB + 4);
    }
    xC[0] = *reinterpret_cast<const float4*>(&xs[r0][0]);
    xC[1] = *reinterpret_cast<const float4*>(&xs[r0 + 1][0]);

    for (int h = 0; h < HB; h += 4) {
        const int hn = (h + 4 < HB) ? h + 4 : 0;   // wrap: harmless reload
        #pragma unroll
        for (int k = 0; k < 4; ++k) {
            wN[k][0] = *reinterpret_cast<const float4*>(wp + (hn + k) * UB);
            wN[k][1] = *reinterpret_cast<const float4*>(wp + (hn + k) * UB + 4);
        }
        xN[0] = *reinterpret_cast<const float4*>(&xs[r0][hn]);
        xN[1] = *reinterpret_cast<const float4*>(&xs[r0 + 1][hn]);
        #pragma unroll
        for (int r = 0; r < 2; ++r) {
            const float xk[4] = {xC[r].x, xC[r].y, xC[r].z, xC[r].w};
            #pragma unroll
            for (int k = 0; k < 4; ++k) {
                acc[r][0] = fmaf(xk[k], wC[k][0].x, acc[r][0]);
                acc[r][1] = fmaf(xk[k], wC[k][0].y, acc[r][1]);
                acc[r][2] = fmaf(xk[k], wC[k][0].z, acc[r][2]);
                acc[r][3] = fmaf(xk[k], wC[k][0].w, acc[r][3]);
                acc[r][4] = fmaf(xk[k], wC[k][1].x, acc[r][4]);
                acc[r][5] = fmaf(xk[k], wC[k][1].y, acc[r][5]);
                acc[r][6] = fmaf(xk[k], wC[k][1].z, acc[r][6]);
                acc[r][7] = fmaf(xk[k], wC[k][1].w, acc[r][7]);
            }
        }
        PINV4(xN[0]); PINV4(xN[1]);
        #pragma unroll
        for (int k = 0; k < 4; ++k) { PINV4(wN[k][0]); PINV4(wN[k][1]); }
        xC[0] = xN[0]; xC[1] = xN[1];
        #pragma unroll
        for (int k = 0; k < 4; ++k) { wC[k][0] = wN[k][0]; wC[k][1] = wN[k][1]; }
    }

    float4 bv0 = *reinterpret_cast<const float4*>(bias + u0);
    float4 bv1 = *reinterpret_cast<const float4*>(bias + u0 + 4);
    const float bvv[8] = {bv0.x, bv0.y, bv0.z, bv0.w, bv1.x, bv1.y, bv1.z, bv1.w};
    const float sh = is_dec ? -16.f : 0.f;
    const int POS  = is_dec ? TD : TE;
    const long bq  = row0 / POS;
    const int pos0 = (int)(row0 % POS);
    float* __restrict__ dstb = is_dec ? Ea : Eb;
    #pragma unroll
    for (int r = 0; r < 2; ++r) {
        float o[8];
        #pragma unroll
        for (int j = 0; j < 8; ++j) o[j] = stage_exp(acc[r][j] + bvv[j], sh);
        const long pr = pos0 + r0 + r;
        *reinterpret_cast<float4*>(&dstb[((bq * 32 + ut * 2 + 0) * (long)POS + pr) * 4]) =
            make_float4(o[0], o[1], o[2], o[3]);
        *reinterpret_cast<float4*>(&dstb[((bq * 32 + ut * 2 + 1) * (long)POS + pr) * 4]) =
            make_float4(o[4], o[5], o[6], o[7]);
    }
}

// ---------------- raw scores (TT=16, unchanged from R9) ----------------
__global__ __launch_bounds__(512) void score_v9(
    const float* __restrict__ Ea4,   // [B][32][TD][4], 2^-16-scaled
    const float4* __restrict__ Eb4,  // [B][32][TE]
    const float* __restrict__ V,     // [UB]
    float* __restrict__ outraw) {    // [B, TD, TE] raw scores
    const int tid = threadIdx.x;
    const int i = blockIdx.x;
    const int xcd = i & 7, j = i >> 3;          // XCD-pinned: 2 b per XCD
    const int b     = 2 * xcd + (j >> 4);
    const int tgrp  = (j >> 1) & 7;
    const int shalf = j & 1;
    const int t0 = tgrp * 16;
    const int s  = shalf * 512 + tid;

    const float*  ab = Ea4 + ((long)b * 32 * TD + t0) * 4;   // + u4*TD*4
    const float4* ep = Eb4 + (long)b * 32 * TE + s;          // + u4*TE
    const float alphav = ALPHA;

    float acc[16];
    #pragma unroll
    for (int t = 0; t < 16; ++t) acc[t] = 0.f;

    float4 a[16], vC, vN, eC, eN;
    vC = *reinterpret_cast<const float4*>(V);
    eC = ep[0];

    for (int u4 = 0; u4 < 32; ++u4) {
        const int p = (u4 + 1 < 32) ? u4 + 1 : 0;   // wrap: harmless reload
        eN = ep[(long)p * TE];
        vN = *reinterpret_cast<const float4*>(V + p * 4);
        const float* _a = ab + (long)u4 * (TD * 4);
        #pragma unroll
        for (int t = 0; t < 16; ++t)
            a[t] = *reinterpret_cast<const float4*>(_a + t * 4);  // uniform
        PINS4(a[15]);   // last-issued: waiting on it drains all a-loads
        #pragma unroll
        for (int t = 0; t < 16; ++t) {
            float4 A = a[t];
            float X0 = fmaf(A.x, eC.x, alphav);
            float X1 = fmaf(A.y, eC.y, alphav);
            float X2 = fmaf(A.z, eC.z, alphav);
            float X3 = fmaf(A.w, eC.w, alphav);
            float P01 = X0 * X1, P23 = X2 * X3;
            float N01 = fmaf(vC.x, X1, vC.y * X0);
            float N23 = fmaf(vC.z, X3, vC.w * X2);
            float N   = fmaf(N01, P23, N23 * P01);
            acc[t] = fmaf(N, __builtin_amdgcn_rcpf(P01 * P23), acc[t]);
        }
        PINV4(eN);
        PINS4(vN);
        eC = eN; vC = vN;
    }

    float* orow = outraw + ((long)b * TD + t0) * TE + s;
    #pragma unroll
    for (int t = 0; t < 16; ++t)
        orow[(long)t * TE] = NEG2ALPHA * acc[t];    // coalesced per row
}

// ---------------- in-place row softmax on d_out (unchanged) ----------------
__global__ __launch_bounds__(1024) void softmax_v9(float* __restrict__ out) {
    const long row = blockIdx.x;             // b*TD + t
    float* p = out + row * TE;
    const int tid = threadIdx.x;
    const int wv = tid >> 6, l = tid & 63;

    float x = p[tid];
    __shared__ float red[16];
    float m = x;
    #pragma unroll
    for (int off = 32; off > 0; off >>= 1) m = fmaxf(m, __shfl_xor(m, off, 64));
    if (l == 0) red[wv] = m;
    __syncthreads();
    #pragma unroll
    for (int k = 0; k < 16; ++k) m = fmaxf(m, red[k]);
    __syncthreads();
    float e = __expf(x - m);
    float si = e;
    #pragma unroll
    for (int off = 32; off > 0; off >>= 1) si += __shfl_xor(si, off, 64);
    if (l == 0) red[wv] = si;
    __syncthreads();
    si = 0.f;
    #pragma unroll
    for (int k = 0; k < 16; ++k) si += red[k];
    p[tid] = e * (1.f / si);
}

extern "C" void kernel_launch(void* const* d_in, const int* in_sizes, int n_in,
                              void* d_out, int out_size, void* d_ws, size_t ws_size,
                              hipStream_t stream) {
    const float* dec = (const float*)d_in[0];
    const float* enc = (const float*)d_in[1];
    const float* W1  = (const float*)d_in[2];
    const float* b1  = (const float*)d_in[3];
    const float* W2  = (const float*)d_in[4];
    const float* b2  = (const float*)d_in[5];
    const float* V   = (const float*)d_in[6];
    // d_in[7] = bv : softmax-invariant, unused
    float* out = (float*)d_out;

    float* Ea = (float*)d_ws;                  // [B][32][TD][4]  1 MB (2^-16-scaled)
    float* Eb = Ea + (long)BB * 32 * TD * 4;   // [B][32][TE][4]  8 MB

    proj_v10<<<DEC_BLOCKS + ENC_BLOCKS, 256, 0, stream>>>(dec, enc, W1, b1, W2, b2, Ea, Eb);
    score_v9<<<256, 512, 0, stream>>>(Ea, (const float4*)Eb, V, out);
    softmax_v9<<<BB * TD, 1024, 0, stream>>>(out);
}

// Round 11
// 78.817 us; speedup vs baseline: 1.8231x; 1.1436x over previous
//
#include <hip/hip_runtime.h>
#include <math.h>

#define HB 256   // hidden
#define UB 128   // attention units
#define BB 16    // batch
#define TD 128   // decoder steps
#define TE 1024  // encoder steps

#define CLAMP_W 7.0f
#define L2E2 2.8853900817779268f        // 2*log2(e)
#define ALPHA 1.52587890625e-05f        // 2^-16 (folded into Ea)
#define NEG2ALPHA (-3.0517578125e-05f)  // -2*ALPHA

// zero-instruction pin: force load completed here (v8-proven on e-stream)
#define PINV(x) asm volatile("" : "+v"(x))
#define PINV4(q) do { PINV((q).x); PINV((q).y); PINV((q).z); PINV((q).w); } while (0)

// staged operand: exp2(2*log2e*clamp(w,+-7) + shift); tanh(a+e)=1-2/(EaEb+1).
// clamp +-7 never triggers on this data; shift=-16 scales Ea so the 4-way
// merged denominator stays bounded. Numerics identical to R4..R10 (passed).
__device__ __forceinline__ float stage_exp(float w, float shift) {
    float t = fminf(fmaxf(w, -CLAMP_W), CLAMP_W);
    return exp2f(fmaf(t, L2E2, shift));
}

// ---------------- projections (dec + enc, one grid) ----------------
// LDS-fed register-tiled GEMM. X tile (32x256, pad 260 -> frag reads conflict-
// free) staged once; W staged through LDS in double-buffered 16-h panels
// (single barrier per panel; next panel's global loads issued BEFORE compute,
// ds_write after -> T14 async-stage, no per-step global dependency anywhere).
// Thread = 8u x 2rows: per 4-h step 8 W-b128 + 2 X-b128 LDS vs 64 FMA.
// 49.6KB LDS -> 3 blocks/CU = 12 waves/CU latency hiding.
#define RWS 32
#define DEC_BLOCKS (BB * TD / RWS)   // 64
#define ENC_BLOCKS (BB * TE / RWS)   // 512

__global__ __launch_bounds__(256) void proj_v11(
    const float* __restrict__ dec, const float* __restrict__ enc,
    const float* __restrict__ W1, const float* __restrict__ b1,
    const float* __restrict__ W2, const float* __restrict__ b2,
    float* __restrict__ Ea, float* __restrict__ Eb) {
    const int blk = blockIdx.x;
    const bool is_dec = blk < DEC_BLOCKS;
    const int rel = is_dec ? blk : blk - DEC_BLOCKS;
    const float* __restrict__ X    = is_dec ? dec : enc;
    const float* __restrict__ W    = is_dec ? W1 : W2;
    const float* __restrict__ bias = is_dec ? b1 : b2;

    __shared__ float xs[RWS][HB + 4];    // 33.3 KB
    __shared__ float ws[2][16 * UB];     // 16 KB, [panel][h*128+u]
    const int tid = threadIdx.x;
    const long row0 = (long)rel * RWS;

    {   // stage X tile (32x256) once, coalesced
        const float4* src = reinterpret_cast<const float4*>(X + row0 * HB);
        #pragma unroll
        for (int i = 0; i < 8; ++i) {
            int idx = i * 256 + tid;
            int r = idx >> 6, c = idx & 63;
            *reinterpret_cast<float4*>(&xs[r][c * 4]) = src[idx];
        }
        // stage W panel 0
        const float4* wsrc = reinterpret_cast<const float4*>(W);
        float4* wdst = reinterpret_cast<float4*>(&ws[0][0]);
        wdst[tid]       = wsrc[tid];
        wdst[tid + 256] = wsrc[tid + 256];
    }
    __syncthreads();

    const int ut = tid & 15, rt = tid >> 4;
    const int u0 = ut * 8;
    const int r0 = rt * 2;

    float acc[2][8];
    #pragma unroll
    for (int r = 0; r < 2; ++r)
        #pragma unroll
        for (int j = 0; j < 8; ++j) acc[r][j] = 0.f;

    for (int p = 0; p < 16; ++p) {       // 16-h panels
        float4 wr0, wr1;
        if (p < 15) {                    // issue next panel's loads early
            const float4* wsrc = reinterpret_cast<const float4*>(W) + (p + 1) * 512;
            wr0 = wsrc[tid];
            wr1 = wsrc[tid + 256];
        }
        const float* wb = &ws[p & 1][0];
        const int hbase = p * 16;
        #pragma unroll
        for (int hh = 0; hh < 16; hh += 4) {
            float4 wf[4][2], xf[2];
            #pragma unroll
            for (int k = 0; k < 4; ++k) {
                wf[k][0] = *reinterpret_cast<const float4*>(wb + (hh + k) * UB + u0);
                wf[k][1] = *reinterpret_cast<const float4*>(wb + (hh + k) * UB + u0 + 4);
            }
            xf[0] = *reinterpret_cast<const float4*>(&xs[r0][hbase + hh]);
            xf[1] = *reinterpret_cast<const float4*>(&xs[r0 + 1][hbase + hh]);
            #pragma unroll
            for (int r = 0; r < 2; ++r) {
                const float xk[4] = {xf[r].x, xf[r].y, xf[r].z, xf[r].w};
                #pragma unroll
                for (int k = 0; k < 4; ++k) {
                    acc[r][0] = fmaf(xk[k], wf[k][0].x, acc[r][0]);
                    acc[r][1] = fmaf(xk[k], wf[k][0].y, acc[r][1]);
                    acc[r][2] = fmaf(xk[k], wf[k][0].z, acc[r][2]);
                    acc[r][3] = fmaf(xk[k], wf[k][0].w, acc[r][3]);
                    acc[r][4] = fmaf(xk[k], wf[k][1].x, acc[r][4]);
                    acc[r][5] = fmaf(xk[k], wf[k][1].y, acc[r][5]);
                    acc[r][6] = fmaf(xk[k], wf[k][1].z, acc[r][6]);
                    acc[r][7] = fmaf(xk[k], wf[k][1].w, acc[r][7]);
                }
            }
        }
        if (p < 15) {                    // write next panel, then one barrier
            float4* wdst = reinterpret_cast<float4*>(&ws[(p + 1) & 1][0]);
            wdst[tid]       = wr0;
            wdst[tid + 256] = wr1;
        }
        __syncthreads();
    }

    float4 bv0 = *reinterpret_cast<const float4*>(bias + u0);
    float4 bv1 = *reinterpret_cast<const float4*>(bias + u0 + 4);
    const float bvv[8] = {bv0.x, bv0.y, bv0.z, bv0.w, bv1.x, bv1.y, bv1.z, bv1.w};
    const float sh = is_dec ? -16.f : 0.f;
    const int POS  = is_dec ? TD : TE;
    const long bq  = row0 / POS;
    const int pos0 = (int)(row0 % POS);
    float* __restrict__ dstb = is_dec ? Ea : Eb;
    #pragma unroll
    for (int r = 0; r < 2; ++r) {
        float o[8];
        #pragma unroll
        for (int j = 0; j < 8; ++j) o[j] = stage_exp(acc[r][j] + bvv[j], sh);
        const long pr = pos0 + r0 + r;
        *reinterpret_cast<float4*>(&dstb[((bq * 32 + ut * 2 + 0) * (long)POS + pr) * 4]) =
            make_float4(o[0], o[1], o[2], o[3]);
        *reinterpret_cast<float4*>(&dstb[((bq * 32 + ut * 2 + 1) * (long)POS + pr) * 4]) =
            make_float4(o[4], o[5], o[6], o[7]);
    }
}

// ---------------- raw scores (TT=16, a/V from LDS broadcast) ----------------
// Grid 256 = [b16][tgrp8][shalf2], block 512. Thread: s = shalf*512+tid,
// 16 t-rows. a-tile (32u4 x 16t x 16B = 8KB) + V staged in LDS ONCE; per-step
// a/V reads are same-address broadcasts (conflict-free, ~200cy < 448cy FMA).
// Only e is VMEM: coalesced dwordx4, depth-1 double-buffered with pin.
__global__ __launch_bounds__(512) void score_v11(
    const float4* __restrict__ Ea4,  // [B][32][TD] float4, 2^-16-scaled
    const float4* __restrict__ Eb4,  // [B][32][TE] float4
    const float4* __restrict__ V4,   // [32] float4
    float* __restrict__ outraw) {    // [B, TD, TE] raw scores
    const int tid = threadIdx.x;
    const int i = blockIdx.x;
    const int xcd = i & 7, j = i >> 3;          // XCD-pinned: 2 b per XCD
    const int b     = 2 * xcd + (j >> 4);
    const int tgrp  = (j >> 1) & 7;
    const int shalf = j & 1;
    const int t0 = tgrp * 16;
    const int s  = shalf * 512 + tid;

    __shared__ float4 as[32 * 16];   // a-tile: [u4][t]
    __shared__ float4 vs[32];
    {
        const int u4 = tid >> 4, tt = tid & 15;
        as[tid] = Ea4[((long)b * 32 + u4) * TD + t0 + tt];
        if (tid < 32) vs[tid] = V4[tid];
    }
    __syncthreads();

    const float4* __restrict__ ep = Eb4 + (long)b * 32 * TE + s;
    const float alphav = ALPHA;

    float acc[16];
    #pragma unroll
    for (int t = 0; t < 16; ++t) acc[t] = 0.f;

    float4 eC = ep[0], eN;
    for (int u4 = 0; u4 < 32; ++u4) {
        const int p = (u4 + 1 < 32) ? u4 + 1 : 0;   // wrap: harmless reload
        eN = ep[(long)p * TE];
        const float4 v4 = vs[u4];                    // broadcast
        #pragma unroll
        for (int t = 0; t < 16; ++t) {
            float4 A = as[u4 * 16 + t];              // broadcast b128
            float X0 = fmaf(A.x, eC.x, alphav);
            float X1 = fmaf(A.y, eC.y, alphav);
            float X2 = fmaf(A.z, eC.z, alphav);
            float X3 = fmaf(A.w, eC.w, alphav);
            float P01 = X0 * X1, P23 = X2 * X3;
            float N01 = fmaf(v4.x, X1, v4.y * X0);
            float N23 = fmaf(v4.z, X3, v4.w * X2);
            float N   = fmaf(N01, P23, N23 * P01);
            acc[t] = fmaf(N, __builtin_amdgcn_rcpf(P01 * P23), acc[t]);
        }
        PINV4(eN);
        eC = eN;
    }

    float* orow = outraw + ((long)b * TD + t0) * TE + s;
    #pragma unroll
    for (int t = 0; t < 16; ++t)
        orow[(long)t * TE] = NEG2ALPHA * acc[t];    // coalesced per row
}

// ---------------- in-place row softmax on d_out (R9-proven) ----------------
__global__ __launch_bounds__(1024) void softmax_v9(float* __restrict__ out) {
    const long row = blockIdx.x;             // b*TD + t
    float* p = out + row * TE;
    const int tid = threadIdx.x;
    const int wv = tid >> 6, l = tid & 63;

    float x = p[tid];
    __shared__ float red[16];
    float m = x;
    #pragma unroll
    for (int off = 32; off > 0; off >>= 1) m = fmaxf(m, __shfl_xor(m, off, 64));
    if (l == 0) red[wv] = m;
    __syncthreads();
    #pragma unroll
    for (int k = 0; k < 16; ++k) m = fmaxf(m, red[k]);
    __syncthreads();
    float e = __expf(x - m);
    float si = e;
    #pragma unroll
    for (int off = 32; off > 0; off >>= 1) si += __shfl_xor(si, off, 64);
    if (l == 0) red[wv] = si;
    __syncthreads();
    si = 0.f;
    #pragma unroll
    for (int k = 0; k < 16; ++k) si += red[k];
    p[tid] = e * (1.f / si);
}

extern "C" void kernel_launch(void* const* d_in, const int* in_sizes, int n_in,
                              void* d_out, int out_size, void* d_ws, size_t ws_size,
                              hipStream_t stream) {
    const float* dec = (const float*)d_in[0];
    const float* enc = (const float*)d_in[1];
    const float* W1  = (const float*)d_in[2];
    const float* b1  = (const float*)d_in[3];
    const float* W2  = (const float*)d_in[4];
    const float* b2  = (const float*)d_in[5];
    const float* V   = (const float*)d_in[6];
    // d_in[7] = bv : softmax-invariant, unused
    float* out = (float*)d_out;

    float* Ea = (float*)d_ws;                  // [B][32][TD][4]  1 MB (2^-16-scaled)
    float* Eb = Ea + (long)BB * 32 * TD * 4;   // [B][32][TE][4]  8 MB

    proj_v11<<<DEC_BLOCKS + ENC_BLOCKS, 256, 0, stream>>>(dec, enc, W1, b1, W2, b2, Ea, Eb);
    score_v11<<<256, 512, 0, stream>>>(
        (const float4*)Ea, (const float4*)Eb, (const float4*)V, out);
    softmax_v9<<<BB * TD, 1024, 0, stream>>>(out);
}

// Round 12
// 76.832 us; speedup vs baseline: 1.8702x; 1.0258x over previous
//
#include <hip/hip_runtime.h>
#include <math.h>

#define HB 256   // hidden
#define UB 128   // attention units
#define BB 16    // batch
#define TD 128   // decoder steps
#define TE 1024  // encoder steps

#define CLAMP_W 7.0f
#define L2E2 2.8853900817779268f        // 2*log2(e)
#define ALPHA 1.52587890625e-05f        // 2^-16 (folded into Ea)
#define NEG2ALPHA (-3.0517578125e-05f)  // -2*ALPHA

// staged operand: exp2(2*log2e*clamp(w,+-7) + shift); tanh(a+e)=1-2/(EaEb+1).
// clamp +-7 never triggers on this data; shift=-16 scales Ea so the 4-way
// merged denominator stays bounded. Numerics identical to R4..R11 (passed).
__device__ __forceinline__ float stage_exp(float w, float shift) {
    float t = fminf(fmaxf(w, -CLAMP_W), CLAMP_W);
    return exp2f(fmaf(t, L2E2, shift));
}

// ---------------- projections (dec + enc, one grid) ----------------
// LDS-budget-correct GEMM: wave = u16-block (W via wave-uniform s_load,
// ZERO LDS/VMEM in the hot loop) x lanes = 64 rows (X from transposed LDS
// tile xt[h][row]: 4 conflict-free ds_read_b32 per 4-h step = ~23cy LDS per
// 128cy VALU -> within the 1-LDS-per-24-FMA budget). Waves split h in halves
// (LDS partial-sum reduce at end); blocks split u in halves for grid balance.
#define DEC_SLABS 32                 // 2048 rows / 64
#define NSLABS 288                   // + 16384/64 enc slabs
#define PROJ_BLOCKS (NSLABS * 2)     // x2 u-halves = 576

__global__ __launch_bounds__(512) void proj_v12(
    const float* __restrict__ dec, const float* __restrict__ enc,
    const float* __restrict__ W1, const float* __restrict__ b1,
    const float* __restrict__ W2, const float* __restrict__ b2,
    float* __restrict__ Ea, float* __restrict__ Eb) {
    const int blk = blockIdx.x;
    const int slab = blk >> 1, uhalf = blk & 1;
    const bool is_dec = slab < DEC_SLABS;
    const int rel = is_dec ? slab : slab - DEC_SLABS;
    const float* __restrict__ X    = is_dec ? dec : enc;
    const float* __restrict__ W    = is_dec ? W1 : W2;
    const float* __restrict__ bias = is_dec ? b1 : b2;

    __shared__ float xt[HB][66];     // transposed X tile [h][row], 67.6 KB
    const int tid = threadIdx.x;
    const long row0 = (long)rel * 64;

    #pragma unroll
    for (int it = 0; it < 8; ++it) {  // stage+transpose 64 rows x 256 h
        int idx = it * 512 + tid;
        int row = idx >> 6, hf4 = idx & 63;
        float4 f = *reinterpret_cast<const float4*>(X + (row0 + row) * HB + hf4 * 4);
        xt[hf4 * 4 + 0][row] = f.x;
        xt[hf4 * 4 + 1][row] = f.y;
        xt[hf4 * 4 + 2][row] = f.z;
        xt[hf4 * 4 + 3][row] = f.w;
    }
    __syncthreads();

    const int l = tid & 63;                                     // row in slab
    const int w = __builtin_amdgcn_readfirstlane(tid >> 6);     // wave 0..7
    const int ub3 = w & 3;                                      // u16 within half
    const int ub  = ub3 + uhalf * 4;                            // 0..7
    const int hh  = w >> 2;                                     // h-half 0/1
    const int u0  = ub * 16;
    const int h0  = hh * 128;

    float acc[16];
    #pragma unroll
    for (int j = 0; j < 16; ++j) acc[j] = 0.f;

    for (int h = 0; h < 128; h += 4) {
        const int hg = h0 + h;
        float4 wf[4][4];                 // wave-uniform -> s_load, no VMEM/LDS
        #pragma unroll
        for (int k = 0; k < 4; ++k)
            #pragma unroll
            for (int q = 0; q < 4; ++q)
                wf[k][q] = *reinterpret_cast<const float4*>(
                    W + (hg + k) * UB + u0 + q * 4);
        float xk[4];
        #pragma unroll
        for (int k = 0; k < 4; ++k) xk[k] = xt[hg + k][l];   // b32, conflict-free
        #pragma unroll
        for (int k = 0; k < 4; ++k)
            #pragma unroll
            for (int q = 0; q < 4; ++q) {
                acc[q * 4 + 0] = fmaf(xk[k], wf[k][q].x, acc[q * 4 + 0]);
                acc[q * 4 + 1] = fmaf(xk[k], wf[k][q].y, acc[q * 4 + 1]);
                acc[q * 4 + 2] = fmaf(xk[k], wf[k][q].z, acc[q * 4 + 2]);
                acc[q * 4 + 3] = fmaf(xk[k], wf[k][q].w, acc[q * 4 + 3]);
            }
    }

    __syncthreads();                     // xt reads done; reuse as reduce buf
    float4* red = reinterpret_cast<float4*>(&xt[0][0]);   // 4ub x 64row x 4 f4
    if (hh == 1) {
        #pragma unroll
        for (int q = 0; q < 4; ++q)
            red[((ub3 * 64 + l) << 2) + q] =
                make_float4(acc[q * 4], acc[q * 4 + 1], acc[q * 4 + 2], acc[q * 4 + 3]);
    }
    __syncthreads();
    if (hh == 0) {
        #pragma unroll
        for (int q = 0; q < 4; ++q) {
            float4 r = red[((ub3 * 64 + l) << 2) + q];
            acc[q * 4 + 0] += r.x; acc[q * 4 + 1] += r.y;
            acc[q * 4 + 2] += r.z; acc[q * 4 + 3] += r.w;
        }
        const float sh = is_dec ? -16.f : 0.f;
        const int POS  = is_dec ? TD : TE;
        const long bq  = row0 / POS;
        const int pos  = (int)(row0 % POS) + l;
        float4* dst4 = reinterpret_cast<float4*>(is_dec ? Ea : Eb);
        #pragma unroll
        for (int q = 0; q < 4; ++q) {    // u4 = ub*4+q, layout [b][u4][pos][4]
            float4 o = make_float4(
                stage_exp(acc[q * 4 + 0] + bias[u0 + q * 4 + 0], sh),
                stage_exp(acc[q * 4 + 1] + bias[u0 + q * 4 + 1], sh),
                stage_exp(acc[q * 4 + 2] + bias[u0 + q * 4 + 2], sh),
                stage_exp(acc[q * 4 + 3] + bias[u0 + q * 4 + 3], sh));
            dst4[(bq * 32 + ub * 4 + q) * (long)POS + pos] = o;   // coalesced
        }
    }
}

// ---------------- raw scores (lanes = 16t x 4s) ----------------
// Grid 1024 = [xcd8][b2][tgrp8][schunk8], block 512 = 8 waves (8/SIMD).
// Lane = (t = l&15, sc = l>>4); lane owns 4 s columns x 1 t-row.
// Per u4-iter: ONE a b128 (16 distinct addrs, 2-way = free) + one uniform V
// read + 4 per-lane e f4 (L2, b-pinned) -> 2 LDS instr per 96 VALU cyc.
__global__ __launch_bounds__(512) void score_v12(
    const float4* __restrict__ Ea4,  // [B][32][TD] f4, 2^-16-scaled
    const float4* __restrict__ Eb4,  // [B][32][TE] f4
    const float4* __restrict__ V4,   // [32] f4
    float* __restrict__ outraw) {    // [B, TD, TE] raw scores
    const int tid = threadIdx.x;
    const int i = blockIdx.x;
    const int xcd = i & 7;
    const int rest = i >> 3;                 // 0..127
    const int b = 2 * xcd + (rest >> 6);     // XCD-pinned batches
    const int sub = rest & 63;
    const int t0 = (sub >> 3) * 16;
    const int schunk = sub & 7;

    __shared__ float4 as[512];   // [u4][t]
    __shared__ float4 vs[32];
    as[tid] = Ea4[((long)b * 32 + (tid >> 4)) * TD + t0 + (tid & 15)];
    if (tid < 32) vs[tid] = V4[tid];
    __syncthreads();

    const int l = tid & 63, wv = tid >> 6;
    const int t = l & 15, sc = l >> 4;
    const int s0 = schunk * 128 + wv * 16 + sc * 4;

    const float4* __restrict__ ep = Eb4 + (long)b * 32 * TE + s0;
    const float alphav = ALPHA;
    float acc[4] = {0.f, 0.f, 0.f, 0.f};

    #pragma unroll 2
    for (int u4 = 0; u4 < 32; ++u4) {
        float4 A  = as[u4 * 16 + t];         // 1 LDS b128, 2-way = free
        float4 v4 = vs[u4];                  // uniform broadcast
        #pragma unroll
        for (int j = 0; j < 4; ++j) {
            float4 e = ep[(long)u4 * TE + j];
            float X0 = fmaf(A.x, e.x, alphav);
            float X1 = fmaf(A.y, e.y, alphav);
            float X2 = fmaf(A.z, e.z, alphav);
            float X3 = fmaf(A.w, e.w, alphav);
            float P01 = X0 * X1, P23 = X2 * X3;
            float N01 = fmaf(v4.x, X1, v4.y * X0);
            float N23 = fmaf(v4.z, X3, v4.w * X2);
            float N   = fmaf(N01, P23, N23 * P01);
            acc[j] = fmaf(N, __builtin_amdgcn_rcpf(P01 * P23), acc[j]);
        }
    }

    float4 o = make_float4(NEG2ALPHA * acc[0], NEG2ALPHA * acc[1],
                           NEG2ALPHA * acc[2], NEG2ALPHA * acc[3]);
    *reinterpret_cast<float4*>(&outraw[((long)b * TD + t0 + t) * TE + s0]) = o;
}

// ---------------- in-place row softmax on d_out (R9-proven) ----------------
__global__ __launch_bounds__(1024) void softmax_v9(float* __restrict__ out) {
    const long row = blockIdx.x;             // b*TD + t
    float* p = out + row * TE;
    const int tid = threadIdx.x;
    const int wv = tid >> 6, l = tid & 63;

    float x = p[tid];
    __shared__ float red[16];
    float m = x;
    #pragma unroll
    for (int off = 32; off > 0; off >>= 1) m = fmaxf(m, __shfl_xor(m, off, 64));
    if (l == 0) red[wv] = m;
    __syncthreads();
    #pragma unroll
    for (int k = 0; k < 16; ++k) m = fmaxf(m, red[k]);
    __syncthreads();
    float e = __expf(x - m);
    float si = e;
    #pragma unroll
    for (int off = 32; off > 0; off >>= 1) si += __shfl_xor(si, off, 64);
    if (l == 0) red[wv] = si;
    __syncthreads();
    si = 0.f;
    #pragma unroll
    for (int k = 0; k < 16; ++k) si += red[k];
    p[tid] = e * (1.f / si);
}

extern "C" void kernel_launch(void* const* d_in, const int* in_sizes, int n_in,
                              void* d_out, int out_size, void* d_ws, size_t ws_size,
                              hipStream_t stream) {
    const float* dec = (const float*)d_in[0];
    const float* enc = (const float*)d_in[1];
    const float* W1  = (const float*)d_in[2];
    const float* b1  = (const float*)d_in[3];
    const float* W2  = (const float*)d_in[4];
    const float* b2  = (const float*)d_in[5];
    const float* V   = (const float*)d_in[6];
    // d_in[7] = bv : softmax-invariant, unused
    float* out = (float*)d_out;

    float* Ea = (float*)d_ws;                  // [B][32][TD][4]  1 MB (2^-16-scaled)
    float* Eb = Ea + (long)BB * 32 * TD * 4;   // [B][32][TE][4]  8 MB

    proj_v12<<<PROJ_BLOCKS, 512, 0, stream>>>(dec, enc, W1, b1, W2, b2, Ea, Eb);
    score_v12<<<1024, 512, 0, stream>>>(
        (const float4*)Ea, (const float4*)Eb, (const float4*)V, out);
    softmax_v9<<<BB * TD, 1024, 0, stream>>>(out);
}

// Round 13
// 67.536 us; speedup vs baseline: 2.1276x; 1.1376x over previous
//
#include <hip/hip_runtime.h>
#include <math.h>

#define HB 256   // hidden
#define UB 128   // attention units
#define BB 16    // batch
#define TD 128   // decoder steps
#define TE 1024  // encoder steps

#define CLAMP_W 7.0f
#define L2E2 2.8853900817779268f        // 2*log2(e)
#define ALPHA 1.52587890625e-05f        // 2^-16 (folded into Ea)
#define NEG2ALPHA (-3.0517578125e-05f)  // -2*ALPHA

// zero-instruction scheduling pins (v8-proven): force load completed here.
#define PINV(x) asm volatile("" : "+v"(x))
#define PINS(x) asm volatile("" : "+s"(x))
#define PINV4(q) do { PINV((q).x); PINV((q).y); PINV((q).z); PINV((q).w); } while (0)
#define PINS4(q) do { PINS((q).x); PINS((q).y); PINS((q).z); PINS((q).w); } while (0)

// staged operand: exp2(2*log2e*clamp(w,+-7) + shift); tanh(a+e)=1-2/(EaEb+1).
// clamp +-7 never triggers on this data; shift=-16 scales Ea so the 4-way
// merged denominator stays bounded. Numerics identical to R4..R12 (passed).
__device__ __forceinline__ float stage_exp(float w, float shift) {
    float t = fminf(fmaxf(w, -CLAMP_W), CLAMP_W);
    return exp2f(fmaf(t, L2E2, shift));
}

// ---------------- projections (dec + enc, one grid; R12-proven ~28us) ------
// Wave = u16-block (W via wave-uniform loads -> scalar pipe, zero LDS/VMEM in
// hot loop) x lanes = 64 rows (X from transposed LDS tile xt[h][row]: 4
// conflict-free ds_read_b32 per 4-h step, within the LDS-pipe budget).
// Waves split h in halves (LDS partial-sum reduce); blocks split u in halves.
#define DEC_SLABS 32                 // 2048 rows / 64
#define NSLABS 288                   // + 16384/64 enc slabs
#define PROJ_BLOCKS (NSLABS * 2)     // x2 u-halves = 576

__global__ __launch_bounds__(512) void proj_v12(
    const float* __restrict__ dec, const float* __restrict__ enc,
    const float* __restrict__ W1, const float* __restrict__ b1,
    const float* __restrict__ W2, const float* __restrict__ b2,
    float* __restrict__ Ea, float* __restrict__ Eb) {
    const int blk = blockIdx.x;
    const int slab = blk >> 1, uhalf = blk & 1;
    const bool is_dec = slab < DEC_SLABS;
    const int rel = is_dec ? slab : slab - DEC_SLABS;
    const float* __restrict__ X    = is_dec ? dec : enc;
    const float* __restrict__ W    = is_dec ? W1 : W2;
    const float* __restrict__ bias = is_dec ? b1 : b2;

    __shared__ float xt[HB][66];     // transposed X tile [h][row]
    const int tid = threadIdx.x;
    const long row0 = (long)rel * 64;

    #pragma unroll
    for (int it = 0; it < 8; ++it) {  // stage+transpose 64 rows x 256 h
        int idx = it * 512 + tid;
        int row = idx >> 6, hf4 = idx & 63;
        float4 f = *reinterpret_cast<const float4*>(X + (row0 + row) * HB + hf4 * 4);
        xt[hf4 * 4 + 0][row] = f.x;
        xt[hf4 * 4 + 1][row] = f.y;
        xt[hf4 * 4 + 2][row] = f.z;
        xt[hf4 * 4 + 3][row] = f.w;
    }
    __syncthreads();

    const int l = tid & 63;                                     // row in slab
    const int w = __builtin_amdgcn_readfirstlane(tid >> 6);     // wave 0..7
    const int ub3 = w & 3;                                      // u16 within half
    const int ub  = ub3 + uhalf * 4;                            // 0..7
    const int hh  = w >> 2;                                     // h-half 0/1
    const int u0  = ub * 16;
    const int h0  = hh * 128;

    float acc[16];
    #pragma unroll
    for (int j = 0; j < 16; ++j) acc[j] = 0.f;

    for (int h = 0; h < 128; h += 4) {
        const int hg = h0 + h;
        float4 wf[4][4];                 // wave-uniform -> scalar loads
        #pragma unroll
        for (int k = 0; k < 4; ++k)
            #pragma unroll
            for (int q = 0; q < 4; ++q)
                wf[k][q] = *reinterpret_cast<const float4*>(
                    W + (hg + k) * UB + u0 + q * 4);
        float xk[4];
        #pragma unroll
        for (int k = 0; k < 4; ++k) xk[k] = xt[hg + k][l];   // b32, conflict-free
        #pragma unroll
        for (int k = 0; k < 4; ++k)
            #pragma unroll
            for (int q = 0; q < 4; ++q) {
                acc[q * 4 + 0] = fmaf(xk[k], wf[k][q].x, acc[q * 4 + 0]);
                acc[q * 4 + 1] = fmaf(xk[k], wf[k][q].y, acc[q * 4 + 1]);
                acc[q * 4 + 2] = fmaf(xk[k], wf[k][q].z, acc[q * 4 + 2]);
                acc[q * 4 + 3] = fmaf(xk[k], wf[k][q].w, acc[q * 4 + 3]);
            }
    }

    __syncthreads();                     // xt reads done; reuse as reduce buf
    float4* red = reinterpret_cast<float4*>(&xt[0][0]);   // 4ub x 64row x 4 f4
    if (hh == 1) {
        #pragma unroll
        for (int q = 0; q < 4; ++q)
            red[((ub3 * 64 + l) << 2) + q] =
                make_float4(acc[q * 4], acc[q * 4 + 1], acc[q * 4 + 2], acc[q * 4 + 3]);
    }
    __syncthreads();
    if (hh == 0) {
        #pragma unroll
        for (int q = 0; q < 4; ++q) {
            float4 r = red[((ub3 * 64 + l) << 2) + q];
            acc[q * 4 + 0] += r.x; acc[q * 4 + 1] += r.y;
            acc[q * 4 + 2] += r.z; acc[q * 4 + 3] += r.w;
        }
        const float sh = is_dec ? -16.f : 0.f;
        const int POS  = is_dec ? TD : TE;
        const long bq  = row0 / POS;
        const int pos  = (int)(row0 % POS) + l;
        float4* dst4 = reinterpret_cast<float4*>(is_dec ? Ea : Eb);
        #pragma unroll
        for (int q = 0; q < 4; ++q) {    // u4 = ub*4+q, layout [b][u4][pos][4]
            float4 o = make_float4(
                stage_exp(acc[q * 4 + 0] + bias[u0 + q * 4 + 0], sh),
                stage_exp(acc[q * 4 + 1] + bias[u0 + q * 4 + 1], sh),
                stage_exp(acc[q * 4 + 2] + bias[u0 + q * 4 + 2], sh),
                stage_exp(acc[q * 4 + 3] + bias[u0 + q * 4 + 3], sh));
            dst4[(bq * 32 + ub * 4 + q) * (long)POS + pos] = o;   // coalesced
        }
    }
}

// ---------------- scores + fused softmax (R8-proven ~30us) ----------------
// Grid 256 (XCD-pinned b), 1024 thr = 16 waves. Thread: s = tid, 8 t-rows.
// Depth-1 software pipeline: next u4's a-tile + V (uniform -> scalar loads)
// + e (per-lane coalesced dwordx4) loaded each iter, pinned AFTER current
// compute. 4-way exact division merge: 13 VALU + 1 rcp per 4u per row.
__global__ __launch_bounds__(1024) void score_v8(
    const float* __restrict__ Ea4,   // [B][32][TD][4], 2^-16-scaled
    const float4* __restrict__ Eb4,  // [B][32][TE]
    const float* __restrict__ V,     // [UB]
    float* __restrict__ out) {       // [B, TD, TE]
    const int tid = threadIdx.x;
    const int wv = tid >> 6, l = tid & 63;
    const int i = blockIdx.x;
    const int b  = 2 * (i & 7) + ((i >> 3) >> 4);
    const int t0 = ((i >> 3) & 15) * 8;

    const float*  ab = Ea4 + ((long)b * 32 * TD) * 4;   // + (u4*TD + t0)*4
    const float4* ep = Eb4 + (long)b * 32 * TE + tid;   // + u4*TE
    const float alphav = ALPHA;

    float acc[8];
    #pragma unroll
    for (int t = 0; t < 8; ++t) acc[t] = 0.f;

    float4 aC[8], aN[8], vC, vN, eC, eN;
#define SLOAD(AB, VB, EB, U4) do {                                        \
        const float* _a = ab + ((long)(U4) * TD + t0) * 4;                \
        _Pragma("unroll")                                                 \
        for (int t = 0; t < 8; ++t)                                       \
            AB[t] = *reinterpret_cast<const float4*>(_a + t * 4);         \
        VB = *reinterpret_cast<const float4*>(V + (U4) * 4);              \
        EB = ep[(long)(U4) * TE];                                         \
    } while (0)

#define SCOMP(AB, VB, EB) do {                                            \
        _Pragma("unroll")                                                 \
        for (int t = 0; t < 8; ++t) {                                     \
            float4 A = AB[t];                                             \
            float X0 = fmaf(A.x, (EB).x, alphav);                         \
            float X1 = fmaf(A.y, (EB).y, alphav);                         \
            float X2 = fmaf(A.z, (EB).z, alphav);                         \
            float X3 = fmaf(A.w, (EB).w, alphav);                         \
            float P01 = X0 * X1, P23 = X2 * X3;                           \
            float N01 = fmaf((VB).x, X1, (VB).y * X0);                    \
            float N23 = fmaf((VB).z, X3, (VB).w * X2);                    \
            float N   = fmaf(N01, P23, N23 * P01);                        \
            acc[t] = fmaf(N, __builtin_amdgcn_rcpf(P01 * P23), acc[t]);   \
        }                                                                 \
    } while (0)

    SLOAD(aC, vC, eC, 0);
    #pragma unroll 2
    for (int u4 = 0; u4 < 32; ++u4) {
        const int p = (u4 + 1 < 32) ? u4 + 1 : 0;   // wrap: harmless reload
        SLOAD(aN, vN, eN, p);
        SCOMP(aC, vC, eC);
        #pragma unroll
        for (int t = 0; t < 8; ++t) PINS4(aN[t]);
        PINS4(vN);
        PINV4(eN);
        #pragma unroll
        for (int t = 0; t < 8; ++t) aC[t] = aN[t];
        vC = vN; eC = eN;
    }
#undef SLOAD
#undef SCOMP

    float sc[8];
    #pragma unroll
    for (int t = 0; t < 8; ++t) sc[t] = NEG2ALPHA * acc[t];

    __shared__ float red[8][16];
    #pragma unroll
    for (int t = 0; t < 8; ++t) {
        float x = sc[t];
        #pragma unroll
        for (int off = 32; off > 0; off >>= 1) x = fmaxf(x, __shfl_xor(x, off, 64));
        if (l == 0) red[t][wv] = x;
    }
    __syncthreads();
    float m[8];
    #pragma unroll
    for (int t = 0; t < 8; ++t) {
        float x = red[t][0];
        #pragma unroll
        for (int k = 1; k < 16; ++k) x = fmaxf(x, red[t][k]);
        m[t] = x;
    }
    __syncthreads();
    #pragma unroll
    for (int t = 0; t < 8; ++t) {
        sc[t] = __expf(sc[t] - m[t]);
        float x = sc[t];
        #pragma unroll
        for (int off = 32; off > 0; off >>= 1) x += __shfl_xor(x, off, 64);
        if (l == 0) red[t][wv] = x;
    }
    __syncthreads();
    #pragma unroll
    for (int t = 0; t < 8; ++t) {
        float x = red[t][0];
        #pragma unroll
        for (int k = 1; k < 16; ++k) x += red[t][k];
        out[((long)b * TD + t0 + t) * TE + tid] = sc[t] * (1.f / x);
    }
}

extern "C" void kernel_launch(void* const* d_in, const int* in_sizes, int n_in,
                              void* d_out, int out_size, void* d_ws, size_t ws_size,
                              hipStream_t stream) {
    const float* dec = (const float*)d_in[0];
    const float* enc = (const float*)d_in[1];
    const float* W1  = (const float*)d_in[2];
    const float* b1  = (const float*)d_in[3];
    const float* W2  = (const float*)d_in[4];
    const float* b2  = (const float*)d_in[5];
    const float* V   = (const float*)d_in[6];
    // d_in[7] = bv : softmax-invariant, unused
    float* out = (float*)d_out;

    float* Ea = (float*)d_ws;                  // [B][32][TD][4]  1 MB (2^-16-scaled)
    float* Eb = Ea + (long)BB * 32 * TD * 4;   // [B][32][TE][4]  8 MB

    proj_v12<<<PROJ_BLOCKS, 512, 0, stream>>>(dec, enc, W1, b1, W2, b2, Ea, Eb);
    score_v8<<<256, 1024, 0, stream>>>(Ea, (const float4*)Eb, V, out);
}